// Round 2
// baseline (2416.911 us; speedup 1.0000x reference)
//
#include <hip/hip_runtime.h>
#include <cstdint>
#include <cstddef>

typedef __attribute__((ext_vector_type(8))) short short8;
typedef __attribute__((ext_vector_type(4))) short short4v;
typedef __attribute__((ext_vector_type(4))) float float4v;

typedef __attribute__((address_space(3))) uint32_t lds_u32;
typedef const __attribute__((address_space(1))) uint32_t gl_u32;

__device__ __forceinline__ short f2bf(float f) {
    union { float f; uint32_t u; } v; v.f = f;
    uint32_t r = v.u + 0x7fffu + ((v.u >> 16) & 1u);
    return (short)(r >> 16);
}
__device__ __forceinline__ float bf2f(short s) {
    union { uint32_t u; float f; } v; v.u = ((uint32_t)(uint16_t)s) << 16;
    return v.f;
}
__device__ __forceinline__ float sigmoidf_(float z) {
    return 1.0f / (1.0f + __expf(-z));
}

// ---------------------------------------------------------------------------
// Prep: x (32768x1024 f32) -> bf16 into Xcat[:, 0:1024] (row stride 1280)
// ---------------------------------------------------------------------------
__global__ __launch_bounds__(256) void xconvert_kernel(const float* __restrict__ x,
                                                       short* __restrict__ Xcat) {
    size_t i = ((size_t)blockIdx.x * 256 + threadIdx.x) * 4;
    size_t r = i >> 10, c = i & 1023;
    float4v v = *(const float4v*)(x + i);
    short4v o;
#pragma unroll
    for (int j = 0; j < 4; ++j) o[j] = f2bf(v[j]);
    *(short4v*)(Xcat + r * 1280 + c) = o;
}

// ---------------------------------------------------------------------------
// Prep: W3b = bf16([Wi; Wf[:, :1024]; Wu[:, :1024]]) (768x1024)
//       Wob = bf16(Wo) (1024x1280)
// ---------------------------------------------------------------------------
__global__ __launch_bounds__(256) void wconvert_kernel(const float* __restrict__ Wi,
                                                       const float* __restrict__ Wf,
                                                       const float* __restrict__ Wu,
                                                       const float* __restrict__ Wo,
                                                       short* __restrict__ W3b,
                                                       short* __restrict__ Wob) {
    int i = blockIdx.x * 256 + threadIdx.x;
    if (i < 768 * 1024) {
        int n = i >> 10, k = i & 1023;
        const float* src = (n < 256) ? (Wi + (size_t)n * 1024 + k)
                         : (n < 512) ? (Wf + (size_t)(n - 256) * 1280 + k)
                                     : (Wu + (size_t)(n - 512) * 1280 + k);
        W3b[i] = f2bf(*src);
    } else {
        int j = i - 768 * 1024;   // 0 .. 1024*1280-1
        Wob[j] = f2bf(Wo[j]);
    }
}

// ---------------------------------------------------------------------------
// Tiled bf16 MFMA GEMM: C[gr][gc] = sum_k A[gr][k]*B[gc][k]
// 128x128 tile, BK=32, 256 threads (4 waves, 2x2), global_load_lds staging.
// EPI=1: bias + silu(first 256 cols), bf16 out to xmfu[gr][gc] ([b*2048+t][768])
// EPI=2: + bo[gc] + x[gr][gc] residual, fp32 out to d_out
// ---------------------------------------------------------------------------
template <int EPI>
__global__ __launch_bounds__(256) void gemm_bt(const short* __restrict__ A,
                                               const short* __restrict__ Bmat,
                                               const int K, const int lda,
                                               const float* __restrict__ bias1,
                                               const float* __restrict__ bias2,
                                               const float* __restrict__ bias3,
                                               const float* __restrict__ xres,
                                               float* __restrict__ outf,
                                               short* __restrict__ outb) {
    __shared__ __align__(16) short As[4096];
    __shared__ __align__(16) short Bs[4096];

    const int tid = threadIdx.x;
    const int lane = tid & 63;
    const int wv = tid >> 6;
    const int wm = wv >> 1, wn = wv & 1;
    const int row15 = lane & 15;
    const int q = lane >> 4;
    const int tileM = blockIdx.x * 128;
    const int tileN = blockIdx.y * 128;

    float4v acc[4][4];
#pragma unroll
    for (int i = 0; i < 4; ++i)
#pragma unroll
        for (int j = 0; j < 4; ++j) acc[i][j] = {0.f, 0.f, 0.f, 0.f};

    const short* aG = A + (size_t)(tileM + (tid >> 2)) * lda + (tid & 3) * 8;
    const short* bG = Bmat + (size_t)(tileN + (tid >> 2)) * K + (tid & 3) * 8;
    const size_t aStep = (size_t)64 * lda;
    const size_t bStep = (size_t)64 * K;

    lds_u32* AsL = (lds_u32*)As;
    lds_u32* BsL = (lds_u32*)Bs;
    const int base1 = wv * 256;
    const int base2 = 1024 + wv * 256;

    for (int kt = 0; kt < K; kt += 32) {
        __builtin_amdgcn_global_load_lds((gl_u32*)aG,           AsL + base1, 16, 0, 0);
        __builtin_amdgcn_global_load_lds((gl_u32*)(aG + aStep), AsL + base2, 16, 0, 0);
        __builtin_amdgcn_global_load_lds((gl_u32*)bG,           BsL + base1, 16, 0, 0);
        __builtin_amdgcn_global_load_lds((gl_u32*)(bG + bStep), BsL + base2, 16, 0, 0);
        aG += 32; bG += 32;
        __syncthreads();

        short8 af[4], bf8[4];
#pragma unroll
        for (int mt = 0; mt < 4; ++mt)
            af[mt] = *(const short8*)(As + (wm * 64 + mt * 16 + row15) * 32 + q * 8);
#pragma unroll
        for (int nt = 0; nt < 4; ++nt)
            bf8[nt] = *(const short8*)(Bs + (wn * 64 + nt * 16 + row15) * 32 + q * 8);
#pragma unroll
        for (int mt = 0; mt < 4; ++mt)
#pragma unroll
            for (int nt = 0; nt < 4; ++nt)
                acc[mt][nt] = __builtin_amdgcn_mfma_f32_16x16x32_bf16(af[mt], bf8[nt], acc[mt][nt], 0, 0, 0);
        __syncthreads();
    }

#pragma unroll
    for (int mt = 0; mt < 4; ++mt) {
#pragma unroll
        for (int nt = 0; nt < 4; ++nt) {
#pragma unroll
            for (int r = 0; r < 4; ++r) {
                const int gr = tileM + wm * 64 + mt * 16 + q * 4 + r;
                const int gc = tileN + wn * 64 + nt * 16 + row15;
                float v = acc[mt][nt][r];
                if (EPI == 1) {
                    float bias = (gc < 256) ? bias1[gc] : (gc < 512) ? bias2[gc - 256] : bias3[gc - 512];
                    float z = v + bias;
                    if (gc < 256) z = z * sigmoidf_(z);   // silu for xm
                    outb[(size_t)gr * 768 + gc] = f2bf(z);
                } else {
                    const size_t idx = (size_t)gr * 1024 + gc;
                    outf[idx] = v + bias1[gc] + xres[idx];
                }
            }
        }
    }
}

// ---------------------------------------------------------------------------
// Sequential scan, ONE WORKGROUP PER BATCH (grid=16, 512 threads = 8 waves).
// SINGLE-PHASE: wave w owns cols n0=w*32..+31 and computes BOTH f- and u-
// logits for them (bfrag[ks][sel][nt] in 128 VGPRs). MFMA C row 0 puts f and
// u for col n0+nt*16+lane in the SAME lane (<16), so sigmoid + h-update are
// pure in-register VALU — no fuz buffer, no phase 2, ONE barrier per step.
// h broadcast: linear 256-short hb, double-buffered (A-frag slot ks*32+q*8+j
// == m, so linear IS fragment order). Loader threads (tid>=256) double-buffer
// 8-step blocks of xm/xf/xu via global_load_lds; one vmcnt(0) per 8 steps.
// ---------------------------------------------------------------------------
__global__ __launch_bounds__(512, 2) void scan_kernel(const float* __restrict__ Wfp,
                                                      const float* __restrict__ Wup,
                                                      const short* __restrict__ xmfu,
                                                      short* __restrict__ Xcat,
                                                      float* __restrict__ hfinal) {
    __shared__ __align__(16) short hb[2][256];      // h bf16, linear == A-frag order
    __shared__ __align__(16) short xstage[2][6144]; // 8 steps x [xm|xf|xu], dbuf

    const int tid = threadIdx.x;
    const int lane = tid & 63;
    const int w = tid >> 6;          // 0..7
    const int n0 = w * 32;           // this wave's 32 output columns
    const int row15 = lane & 15;
    const int q = lane >> 4;
    const int b = blockIdx.x;

    const short* xm_b = xmfu + (size_t)b * 1572864;   // [b][2048][768]

    ((short*)hb)[tid] = 0;           // zero both h buffers (512 shorts)

    // B-fragments for BOTH gates: B[k][n] = WH[n][1024+k]; lane holds
    // n = n0 + nt*16 + row15, k = ks*32 + q*8 + j.  32 short8 = 128 VGPRs.
    short8 bfrag[8][2][2];           // [ks][sel:f,u][nt]
#pragma unroll
    for (int ks = 0; ks < 8; ++ks)
#pragma unroll
        for (int sel = 0; sel < 2; ++sel)
#pragma unroll
            for (int nt = 0; nt < 2; ++nt) {
                const float* WH = sel ? Wup : Wfp;
                const float* src = WH + (size_t)(n0 + nt * 16 + row15) * 1280 + 1024 + ks * 32 + q * 8;
                float4v v0 = *(const float4v*)(src);
                float4v v1 = *(const float4v*)(src + 4);
                short8 v;
#pragma unroll
                for (int j = 0; j < 4; ++j) { v[j] = f2bf(v0[j]); v[j + 4] = f2bf(v1[j]); }
                bfrag[ks][sel][nt] = v;
            }

    // loaders: threads 256..511 stage 8-step blocks (12288 B) of xmfu
    const bool isLoader = (tid >= 256);
    const int lw = (tid - 256) >> 6;                  // loader wave 0..3
    lds_u32* xl = (lds_u32*)(&xstage[0][0]);

    if (isLoader) {
#pragma unroll
        for (int i = 0; i < 3; ++i)
            __builtin_amdgcn_global_load_lds((gl_u32*)(xm_b + i * 2048 + lw * 512 + lane * 8),
                                             xl + (i * 1024 + lw * 256), 16, 0, 0);
        __builtin_amdgcn_sched_barrier(0);
        asm volatile("s_waitcnt vmcnt(0)" ::: "memory");
        __builtin_amdgcn_sched_barrier(0);
    }
    __builtin_amdgcn_sched_barrier(0);
    asm volatile("s_waitcnt lgkmcnt(0)" ::: "memory");
    __builtin_amdgcn_sched_barrier(0);
    __builtin_amdgcn_s_barrier();
    __builtin_amdgcn_sched_barrier(0);

    // in-register recurrence state: lane l (<16) of wave w owns
    // h[m1 = n0 + l] and h[m2 = n0 + 16 + l]
    float h1 = 0.f, h2 = 0.f;
    const int m1 = n0 + row15;
    short* Xout1 = Xcat + (size_t)b * 2048 * 1280 + 1024 + m1;
    short* Xout2 = Xout1 + 16;

    short8 afr = {0, 0, 0, 0, 0, 0, 0, 0};   // A-frag; stays 0 in rows 1-15

#pragma unroll 1
    for (int j = 0; j < 256; ++j) {
        const int buf = j & 1;
        if (isLoader && (j + 1 < 256)) {
            const short* src = xm_b + (size_t)(j + 1) * 6144;
#pragma unroll
            for (int i = 0; i < 3; ++i)
                __builtin_amdgcn_global_load_lds((gl_u32*)(src + i * 2048 + lw * 512 + lane * 8),
                                                 xl + ((buf ^ 1) * 3072 + i * 1024 + lw * 256), 16, 0, 0);
        }
        const short* xs = &xstage[buf][0];
#pragma unroll
        for (int s = 0; s < 8; ++s) {
            const int p = s & 1;     // t = j*8+s; t&1 == s&1
            // per-lane xm / logit-bias loads (stable xstage; hide under MFMA)
            float xmv1, xmv2, zf1, zf2, zu1, zu2;
            if (lane < 16) {
                xmv1 = bf2f(xs[s * 768 + m1]);
                zf1  = bf2f(xs[s * 768 + 256 + m1]);
                zu1  = bf2f(xs[s * 768 + 512 + m1]);
                xmv2 = bf2f(xs[s * 768 + 16 + m1]);
                zf2  = bf2f(xs[s * 768 + 272 + m1]);
                zu2  = bf2f(xs[s * 768 + 528 + m1]);
            }
            // logits for this wave's 32 cols, both gates
            float4v af0 = {0.f, 0.f, 0.f, 0.f}, af1 = {0.f, 0.f, 0.f, 0.f};
            float4v au0 = {0.f, 0.f, 0.f, 0.f}, au1 = {0.f, 0.f, 0.f, 0.f};
#pragma unroll
            for (int ks = 0; ks < 8; ++ks) {
                if (row15 == 0)
                    afr = *(const short8*)(&hb[p][ks * 32 + q * 8]);
                af0 = __builtin_amdgcn_mfma_f32_16x16x32_bf16(afr, bfrag[ks][0][0], af0, 0, 0, 0);
                af1 = __builtin_amdgcn_mfma_f32_16x16x32_bf16(afr, bfrag[ks][0][1], af1, 0, 0, 0);
                au0 = __builtin_amdgcn_mfma_f32_16x16x32_bf16(afr, bfrag[ks][1][0], au0, 0, 0, 0);
                au1 = __builtin_amdgcn_mfma_f32_16x16x32_bf16(afr, bfrag[ks][1][1], au1, 0, 0, 0);
            }
            // row 0 (the real batch row) = lanes 0..15, reg 0
            if (lane < 16) {
                const float f1 = sigmoidf_(af0[0] + zf1);
                const float u1 = sigmoidf_(au0[0] + zu1);
                const float f2 = sigmoidf_(af1[0] + zf2);
                const float u2 = sigmoidf_(au1[0] + zu2);
                h1 = f1 * h1 + u1 * xmv1;
                h2 = f2 * h2 + u2 * xmv2;
                const short s1 = f2bf(h1), s2 = f2bf(h2);
                hb[p ^ 1][m1] = s1;
                hb[p ^ 1][m1 + 16] = s2;
                const size_t off = (size_t)(j * 8 + s) * 1280;
                Xout1[off] = s1;        // H -> Xcat, stays in flight
                Xout2[off] = s2;
            }
            if (s == 7 && isLoader) {   // next block's loads must be in LDS
                __builtin_amdgcn_sched_barrier(0);
                asm volatile("s_waitcnt vmcnt(0)" ::: "memory");
                __builtin_amdgcn_sched_barrier(0);
            }
            __builtin_amdgcn_sched_barrier(0);
            asm volatile("s_waitcnt lgkmcnt(0)" ::: "memory");
            __builtin_amdgcn_sched_barrier(0);
            __builtin_amdgcn_s_barrier();
            __builtin_amdgcn_sched_barrier(0);
        }
    }
    if (lane < 16) {
        hfinal[b * 256 + m1] = h1;
        hfinal[b * 256 + m1 + 16] = h2;
    }
}

// ---------------------------------------------------------------------------
extern "C" void kernel_launch(void* const* d_in, const int* in_sizes, int n_in,
                              void* d_out, int out_size, void* d_ws, size_t ws_size,
                              hipStream_t stream) {
    const float* x  = (const float*)d_in[0];
    const float* Wi = (const float*)d_in[1];
    const float* bi = (const float*)d_in[2];
    const float* Wf = (const float*)d_in[3];
    const float* bf = (const float*)d_in[4];
    const float* Wu = (const float*)d_in[5];
    const float* bu = (const float*)d_in[6];
    const float* Wo = (const float*)d_in[7];
    const float* bo = (const float*)d_in[8];
    float* out = (float*)d_out;   // 33554432 outs + 4096 h_final

    char* ws = (char*)d_ws;
    short* Xcat = (short*)ws;                                  // 32768*1280*2 = 83,886,080 B
    short* xmfu = (short*)(ws + 83886080ULL);                  // [b][t][768]: 50,331,648 B
    short* W3b  = (short*)(ws + 83886080ULL + 50331648ULL);    // 768*1024*2
    short* Wob  = (short*)(ws + 83886080ULL + 50331648ULL + 1572864ULL); // 1024*1280*2

    xconvert_kernel<<<dim3(32768), dim3(256), 0, stream>>>(x, Xcat);
    wconvert_kernel<<<dim3(8192), dim3(256), 0, stream>>>(Wi, Wf, Wu, Wo, W3b, Wob);
    // xm/xf/xu: (32768 x 768) = Xcat[:, :1024] @ W3b^T (+bias, silu on xm)
    gemm_bt<1><<<dim3(256, 6), dim3(256), 0, stream>>>(Xcat, W3b, 1024, 1280,
                                                       bi, bf, bu, nullptr, nullptr, xmfu);
    // sequential recurrence: 16 independent batch workgroups
    scan_kernel<<<dim3(16), dim3(512), 0, stream>>>(Wf, Wu, xmfu, Xcat, out + 33554432);
    // out = x + Xcat @ Wo^T + bo   (covers x@Wo[:,:d]^T + H@WoH^T)
    gemm_bt<2><<<dim3(256, 8), dim3(256), 0, stream>>>(Xcat, Wob, 1280, 1280,
                                                       bo, nullptr, nullptr, x, out, nullptr);
}

// Round 3
// 2404.040 us; speedup vs baseline: 1.0054x; 1.0054x over previous
//
#include <hip/hip_runtime.h>
#include <cstdint>
#include <cstddef>

typedef __attribute__((ext_vector_type(8))) short short8;
typedef __attribute__((ext_vector_type(4))) short short4v;
typedef __attribute__((ext_vector_type(4))) float float4v;

typedef __attribute__((address_space(3))) uint32_t lds_u32;
typedef const __attribute__((address_space(1))) uint32_t gl_u32;

__device__ __forceinline__ short f2bf(float f) {
    union { float f; uint32_t u; } v; v.f = f;
    uint32_t r = v.u + 0x7fffu + ((v.u >> 16) & 1u);
    return (short)(r >> 16);
}
__device__ __forceinline__ float bf2f(short s) {
    union { uint32_t u; float f; } v; v.u = ((uint32_t)(uint16_t)s) << 16;
    return v.f;
}
__device__ __forceinline__ float sigmoidf_(float z) {
    return 1.0f / (1.0f + __expf(-z));
}

// ---------------------------------------------------------------------------
// Prep: x (32768x1024 f32) -> bf16 into Xcat[:, 0:1024] (row stride 1280)
// ---------------------------------------------------------------------------
__global__ __launch_bounds__(256) void xconvert_kernel(const float* __restrict__ x,
                                                       short* __restrict__ Xcat) {
    size_t i = ((size_t)blockIdx.x * 256 + threadIdx.x) * 4;
    size_t r = i >> 10, c = i & 1023;
    float4v v = *(const float4v*)(x + i);
    short4v o;
#pragma unroll
    for (int j = 0; j < 4; ++j) o[j] = f2bf(v[j]);
    *(short4v*)(Xcat + r * 1280 + c) = o;
}

// ---------------------------------------------------------------------------
// Prep: W3b = bf16([Wi; Wf[:, :1024]; Wu[:, :1024]]) (768x1024)
//       Wob = bf16(Wo) (1024x1280)
// ---------------------------------------------------------------------------
__global__ __launch_bounds__(256) void wconvert_kernel(const float* __restrict__ Wi,
                                                       const float* __restrict__ Wf,
                                                       const float* __restrict__ Wu,
                                                       const float* __restrict__ Wo,
                                                       short* __restrict__ W3b,
                                                       short* __restrict__ Wob) {
    int i = blockIdx.x * 256 + threadIdx.x;
    if (i < 768 * 1024) {
        int n = i >> 10, k = i & 1023;
        const float* src = (n < 256) ? (Wi + (size_t)n * 1024 + k)
                         : (n < 512) ? (Wf + (size_t)(n - 256) * 1280 + k)
                                     : (Wu + (size_t)(n - 512) * 1280 + k);
        W3b[i] = f2bf(*src);
    } else {
        int j = i - 768 * 1024;   // 0 .. 1024*1280-1
        Wob[j] = f2bf(Wo[j]);
    }
}

// ---------------------------------------------------------------------------
// Tiled bf16 MFMA GEMM: C[gr][gc] = sum_k A[gr][k]*B[gc][k]
// 128x128 tile, BK=32, 256 threads (4 waves, 2x2), global_load_lds staging.
// EPI=1: bias + silu(first 256 cols), bf16 out to xmfu[gr][gc] ([b*2048+t][768])
// EPI=2: + bo[gc] + x[gr][gc] residual, fp32 out to d_out
// ---------------------------------------------------------------------------
template <int EPI>
__global__ __launch_bounds__(256) void gemm_bt(const short* __restrict__ A,
                                               const short* __restrict__ Bmat,
                                               const int K, const int lda,
                                               const float* __restrict__ bias1,
                                               const float* __restrict__ bias2,
                                               const float* __restrict__ bias3,
                                               const float* __restrict__ xres,
                                               float* __restrict__ outf,
                                               short* __restrict__ outb) {
    __shared__ __align__(16) short As[4096];
    __shared__ __align__(16) short Bs[4096];

    const int tid = threadIdx.x;
    const int lane = tid & 63;
    const int wv = tid >> 6;
    const int wm = wv >> 1, wn = wv & 1;
    const int row15 = lane & 15;
    const int q = lane >> 4;
    const int tileM = blockIdx.x * 128;
    const int tileN = blockIdx.y * 128;

    float4v acc[4][4];
#pragma unroll
    for (int i = 0; i < 4; ++i)
#pragma unroll
        for (int j = 0; j < 4; ++j) acc[i][j] = {0.f, 0.f, 0.f, 0.f};

    const short* aG = A + (size_t)(tileM + (tid >> 2)) * lda + (tid & 3) * 8;
    const short* bG = Bmat + (size_t)(tileN + (tid >> 2)) * K + (tid & 3) * 8;
    const size_t aStep = (size_t)64 * lda;
    const size_t bStep = (size_t)64 * K;

    lds_u32* AsL = (lds_u32*)As;
    lds_u32* BsL = (lds_u32*)Bs;
    const int base1 = wv * 256;
    const int base2 = 1024 + wv * 256;

    for (int kt = 0; kt < K; kt += 32) {
        __builtin_amdgcn_global_load_lds((gl_u32*)aG,           AsL + base1, 16, 0, 0);
        __builtin_amdgcn_global_load_lds((gl_u32*)(aG + aStep), AsL + base2, 16, 0, 0);
        __builtin_amdgcn_global_load_lds((gl_u32*)bG,           BsL + base1, 16, 0, 0);
        __builtin_amdgcn_global_load_lds((gl_u32*)(bG + bStep), BsL + base2, 16, 0, 0);
        aG += 32; bG += 32;
        __syncthreads();

        short8 af[4], bf8[4];
#pragma unroll
        for (int mt = 0; mt < 4; ++mt)
            af[mt] = *(const short8*)(As + (wm * 64 + mt * 16 + row15) * 32 + q * 8);
#pragma unroll
        for (int nt = 0; nt < 4; ++nt)
            bf8[nt] = *(const short8*)(Bs + (wn * 64 + nt * 16 + row15) * 32 + q * 8);
#pragma unroll
        for (int mt = 0; mt < 4; ++mt)
#pragma unroll
            for (int nt = 0; nt < 4; ++nt)
                acc[mt][nt] = __builtin_amdgcn_mfma_f32_16x16x32_bf16(af[mt], bf8[nt], acc[mt][nt], 0, 0, 0);
        __syncthreads();
    }

#pragma unroll
    for (int mt = 0; mt < 4; ++mt) {
#pragma unroll
        for (int nt = 0; nt < 4; ++nt) {
#pragma unroll
            for (int r = 0; r < 4; ++r) {
                const int gr = tileM + wm * 64 + mt * 16 + q * 4 + r;
                const int gc = tileN + wn * 64 + nt * 16 + row15;
                float v = acc[mt][nt][r];
                if (EPI == 1) {
                    float bias = (gc < 256) ? bias1[gc] : (gc < 512) ? bias2[gc - 256] : bias3[gc - 512];
                    float z = v + bias;
                    if (gc < 256) z = z * sigmoidf_(z);   // silu for xm
                    outb[(size_t)gr * 768 + gc] = f2bf(z);
                } else {
                    const size_t idx = (size_t)gr * 1024 + gc;
                    outf[idx] = v + bias1[gc] + xres[idx];
                }
            }
        }
    }
}

// ---------------------------------------------------------------------------
// Sequential scan, ONE WORKGROUP PER BATCH (grid=16, 512 threads = 8 waves).
// Single-phase (R2 dataflow) with GLOBALLY-SILENT compute steps:
//  - wave w owns cols w*32..+31, computes f- AND u-logits (bfrag in 128 VGPRs);
//    sigmoid + h-update in-register in lanes<16; ONE barrier per step.
//  - h history lives in hist[2][8][256] LDS (linear == A-frag order); step s
//    reads hist[jb][s-1] (block-parity dbuf) and writes hist[jb][s].
//  - waves 0-3: global_load_lds staging of xm/xf/xu blocks; their vmcnt(0) at
//    s==7 sees ONLY 7-step-aged loads (no stores ever -> no fresh-store drain).
//  - waves 4-7: once per block, copy the COMPLETED previous hist buffer to
//    Xcat as coalesced dwordx4 stores; never wait on vmcnt.
//  - MFMA dependent chains split even/odd ks: 8 chains of depth 4 (+ tail add)
//    instead of 4 chains of depth 8. setprio(1) around the MFMA cluster.
// ---------------------------------------------------------------------------
__global__ __launch_bounds__(512, 2) void scan_kernel(const float* __restrict__ Wfp,
                                                      const float* __restrict__ Wup,
                                                      const short* __restrict__ xmfu,
                                                      short* __restrict__ Xcat,
                                                      float* __restrict__ hfinal) {
    __shared__ __align__(16) short hist[2][8][256];   // 8 KB: h bf16 history
    __shared__ __align__(16) short xstage[2][6144];   // 24 KB: 8 steps x [xm|xf|xu]

    const int tid = threadIdx.x;
    const int lane = tid & 63;
    const int w = tid >> 6;          // 0..7
    const int n0 = w * 32;           // this wave's 32 output columns
    const int row15 = lane & 15;
    const int q = lane >> 4;
    const int b = blockIdx.x;

    const short* xm_b = xmfu + (size_t)b * 1572864;   // [b][2048][768]
    short* XoutBase = Xcat + (size_t)b * 2048 * 1280 + 1024;

    for (int i = tid; i < 4096; i += 512) ((short*)hist)[i] = 0;

    // B-fragments for BOTH gates: B[k][n] = WH[n][1024+k]; lane holds
    // n = n0 + nt*16 + row15, k = ks*32 + q*8 + j.  32 short8 = 128 VGPRs.
    short8 bfrag[8][2][2];           // [ks][sel:f,u][nt]
#pragma unroll
    for (int ks = 0; ks < 8; ++ks)
#pragma unroll
        for (int sel = 0; sel < 2; ++sel)
#pragma unroll
            for (int nt = 0; nt < 2; ++nt) {
                const float* WH = sel ? Wup : Wfp;
                const float* src = WH + (size_t)(n0 + nt * 16 + row15) * 1280 + 1024 + ks * 32 + q * 8;
                float4v v0 = *(const float4v*)(src);
                float4v v1 = *(const float4v*)(src + 4);
                short8 v;
#pragma unroll
                for (int j = 0; j < 4; ++j) { v[j] = f2bf(v0[j]); v[j + 4] = f2bf(v1[j]); }
                bfrag[ks][sel][nt] = v;
            }

    lds_u32* xl = (lds_u32*)(&xstage[0][0]);
    const bool isLoader = (w < 4);   // waves 0-3 stage xmfu blocks
    const bool isCopier = (w >= 4);  // waves 4-7 copy hist -> Xcat

    if (isLoader) {
#pragma unroll
        for (int i = 0; i < 3; ++i)
            __builtin_amdgcn_global_load_lds((gl_u32*)(xm_b + i * 2048 + w * 512 + lane * 8),
                                             xl + (i * 1024 + w * 256), 16, 0, 0);
        __builtin_amdgcn_sched_barrier(0);
        asm volatile("s_waitcnt vmcnt(0)" ::: "memory");
        __builtin_amdgcn_sched_barrier(0);
    }
    __builtin_amdgcn_sched_barrier(0);
    asm volatile("s_waitcnt lgkmcnt(0)" ::: "memory");
    __builtin_amdgcn_sched_barrier(0);
    __builtin_amdgcn_s_barrier();
    __builtin_amdgcn_sched_barrier(0);

    // in-register recurrence state: lane l (<16) of wave w owns
    // h[m1 = n0 + l] and h[m2 = n0 + 16 + l]
    float h1 = 0.f, h2 = 0.f;
    const int m1 = n0 + row15;

    // copier geometry: this lane copies hist row s0r (2 rows per wave)
    const int s0r = 2 * (w - 4) + (lane >> 5);
    const int cOff = (lane & 31) * 8;

    short8 afr = {0, 0, 0, 0, 0, 0, 0, 0};   // A-frag; stays 0 in rows 1-15

#pragma unroll 1
    for (int j = 0; j < 256; ++j) {
        const int jb = j & 1;
        if (isLoader && (j + 1 < 256)) {
            const short* src = xm_b + (size_t)(j + 1) * 6144;
#pragma unroll
            for (int i = 0; i < 3; ++i)
                __builtin_amdgcn_global_load_lds((gl_u32*)(src + i * 2048 + w * 512 + lane * 8),
                                                 xl + ((jb ^ 1) * 3072 + i * 1024 + w * 256), 16, 0, 0);
        }
        if (isCopier && j >= 1) {
            // previous block's h (parity jb^1) -> Xcat, coalesced 512B rows
            short8 hv = *(const short8*)(&hist[jb ^ 1][s0r][cOff]);
            *(short8*)(XoutBase + (size_t)(8 * (j - 1) + s0r) * 1280 + cOff) = hv;
        }
        const short* xs = &xstage[jb][0];
#pragma unroll
        for (int s = 0; s < 8; ++s) {
            // per-lane xm / logit-bias loads (stable xstage; hide under MFMA)
            float xmv1 = 0.f, xmv2 = 0.f, zf1 = 0.f, zf2 = 0.f, zu1 = 0.f, zu2 = 0.f;
            if (lane < 16) {
                xmv1 = bf2f(xs[s * 768 + m1]);
                zf1  = bf2f(xs[s * 768 + 256 + m1]);
                zu1  = bf2f(xs[s * 768 + 512 + m1]);
                xmv2 = bf2f(xs[s * 768 + 16 + m1]);
                zf2  = bf2f(xs[s * 768 + 272 + m1]);
                zu2  = bf2f(xs[s * 768 + 528 + m1]);
            }
            // h_{t-1} source: previous step's row (block-parity dbuf)
            const short* hprev = (s == 0) ? &hist[jb ^ 1][7][0] : &hist[jb][s - 1][0];

            // logits for this wave's 32 cols, both gates; even/odd-ks chain split
            float4v acc[2][2][2];   // [sel][nt][half]
#pragma unroll
            for (int sel = 0; sel < 2; ++sel)
#pragma unroll
                for (int nt = 0; nt < 2; ++nt)
#pragma unroll
                    for (int hf = 0; hf < 2; ++hf) acc[sel][nt][hf] = {0.f, 0.f, 0.f, 0.f};

            __builtin_amdgcn_s_setprio(1);
#pragma unroll
            for (int ks = 0; ks < 8; ++ks) {
                if (row15 == 0)
                    afr = *(const short8*)(hprev + ks * 32 + q * 8);
                const int hf = ks & 1;
                acc[0][0][hf] = __builtin_amdgcn_mfma_f32_16x16x32_bf16(afr, bfrag[ks][0][0], acc[0][0][hf], 0, 0, 0);
                acc[0][1][hf] = __builtin_amdgcn_mfma_f32_16x16x32_bf16(afr, bfrag[ks][0][1], acc[0][1][hf], 0, 0, 0);
                acc[1][0][hf] = __builtin_amdgcn_mfma_f32_16x16x32_bf16(afr, bfrag[ks][1][0], acc[1][0][hf], 0, 0, 0);
                acc[1][1][hf] = __builtin_amdgcn_mfma_f32_16x16x32_bf16(afr, bfrag[ks][1][1], acc[1][1][hf], 0, 0, 0);
            }
            __builtin_amdgcn_s_setprio(0);

            // row 0 (the real batch row) = lanes 0..15, reg 0
            if (lane < 16) {
                const float f1 = sigmoidf_(acc[0][0][0][0] + acc[0][0][1][0] + zf1);
                const float u1 = sigmoidf_(acc[1][0][0][0] + acc[1][0][1][0] + zu1);
                const float f2 = sigmoidf_(acc[0][1][0][0] + acc[0][1][1][0] + zf2);
                const float u2 = sigmoidf_(acc[1][1][0][0] + acc[1][1][1][0] + zu2);
                h1 = f1 * h1 + u1 * xmv1;
                h2 = f2 * h2 + u2 * xmv2;
                hist[jb][s][m1] = f2bf(h1);
                hist[jb][s][m1 + 16] = f2bf(h2);
            }
            if (s == 7 && isLoader) {   // next block's loads must be in LDS
                __builtin_amdgcn_sched_barrier(0);
                asm volatile("s_waitcnt vmcnt(0)" ::: "memory");
                __builtin_amdgcn_sched_barrier(0);
            }
            __builtin_amdgcn_sched_barrier(0);
            asm volatile("s_waitcnt lgkmcnt(0)" ::: "memory");
            __builtin_amdgcn_sched_barrier(0);
            __builtin_amdgcn_s_barrier();
            __builtin_amdgcn_sched_barrier(0);
        }
    }
    // tail: copy the final block's h (parity 1, t = 2040..2047)
    if (isCopier) {
        short8 hv = *(const short8*)(&hist[1][s0r][cOff]);
        *(short8*)(XoutBase + (size_t)(2040 + s0r) * 1280 + cOff) = hv;
    }
    if (lane < 16) {
        hfinal[b * 256 + m1] = h1;
        hfinal[b * 256 + m1 + 16] = h2;
    }
}

// ---------------------------------------------------------------------------
extern "C" void kernel_launch(void* const* d_in, const int* in_sizes, int n_in,
                              void* d_out, int out_size, void* d_ws, size_t ws_size,
                              hipStream_t stream) {
    const float* x  = (const float*)d_in[0];
    const float* Wi = (const float*)d_in[1];
    const float* bi = (const float*)d_in[2];
    const float* Wf = (const float*)d_in[3];
    const float* bf = (const float*)d_in[4];
    const float* Wu = (const float*)d_in[5];
    const float* bu = (const float*)d_in[6];
    const float* Wo = (const float*)d_in[7];
    const float* bo = (const float*)d_in[8];
    float* out = (float*)d_out;   // 33554432 outs + 4096 h_final

    char* ws = (char*)d_ws;
    short* Xcat = (short*)ws;                                  // 32768*1280*2 = 83,886,080 B
    short* xmfu = (short*)(ws + 83886080ULL);                  // [b][t][768]: 50,331,648 B
    short* W3b  = (short*)(ws + 83886080ULL + 50331648ULL);    // 768*1024*2
    short* Wob  = (short*)(ws + 83886080ULL + 50331648ULL + 1572864ULL); // 1024*1280*2

    xconvert_kernel<<<dim3(32768), dim3(256), 0, stream>>>(x, Xcat);
    wconvert_kernel<<<dim3(8192), dim3(256), 0, stream>>>(Wi, Wf, Wu, Wo, W3b, Wob);
    // xm/xf/xu: (32768 x 768) = Xcat[:, :1024] @ W3b^T (+bias, silu on xm)
    gemm_bt<1><<<dim3(256, 6), dim3(256), 0, stream>>>(Xcat, W3b, 1024, 1280,
                                                       bi, bf, bu, nullptr, nullptr, xmfu);
    // sequential recurrence: 16 independent batch workgroups
    scan_kernel<<<dim3(16), dim3(512), 0, stream>>>(Wf, Wu, xmfu, Xcat, out + 33554432);
    // out = x + Xcat @ Wo^T + bo   (covers x@Wo[:,:d]^T + H@WoH^T)
    gemm_bt<2><<<dim3(256, 8), dim3(256), 0, stream>>>(Xcat, Wob, 1280, 1280,
                                                       bo, nullptr, nullptr, x, out, nullptr);
}

// Round 4
// 2150.528 us; speedup vs baseline: 1.1239x; 1.1179x over previous
//
#include <hip/hip_runtime.h>
#include <cstdint>
#include <cstddef>

typedef __attribute__((ext_vector_type(8))) short short8;
typedef __attribute__((ext_vector_type(4))) short short4v;
typedef __attribute__((ext_vector_type(4))) float float4v;

typedef __attribute__((address_space(3))) uint32_t lds_u32;
typedef const __attribute__((address_space(1))) uint32_t gl_u32;

__device__ __forceinline__ short f2bf(float f) {
    union { float f; uint32_t u; } v; v.f = f;
    uint32_t r = v.u + 0x7fffu + ((v.u >> 16) & 1u);
    return (short)(r >> 16);
}
__device__ __forceinline__ float bf2f(short s) {
    union { uint32_t u; float f; } v; v.u = ((uint32_t)(uint16_t)s) << 16;
    return v.f;
}
__device__ __forceinline__ float sigmoidf_(float z) {
    return 1.0f / (1.0f + __expf(-z));
}

// ---------------------------------------------------------------------------
// Prep: x (32768x1024 f32) -> bf16 into Xcat[:, 0:1024] (row stride 1280)
// ---------------------------------------------------------------------------
__global__ __launch_bounds__(256) void xconvert_kernel(const float* __restrict__ x,
                                                       short* __restrict__ Xcat) {
    size_t i = ((size_t)blockIdx.x * 256 + threadIdx.x) * 4;
    size_t r = i >> 10, c = i & 1023;
    float4v v = *(const float4v*)(x + i);
    short4v o;
#pragma unroll
    for (int j = 0; j < 4; ++j) o[j] = f2bf(v[j]);
    *(short4v*)(Xcat + r * 1280 + c) = o;
}

// ---------------------------------------------------------------------------
// Prep: W3b = bf16([Wi; Wf[:, :1024]; Wu[:, :1024]]) (768x1024)
//       Wob = bf16(Wo) (1024x1280)
// ---------------------------------------------------------------------------
__global__ __launch_bounds__(256) void wconvert_kernel(const float* __restrict__ Wi,
                                                       const float* __restrict__ Wf,
                                                       const float* __restrict__ Wu,
                                                       const float* __restrict__ Wo,
                                                       short* __restrict__ W3b,
                                                       short* __restrict__ Wob) {
    int i = blockIdx.x * 256 + threadIdx.x;
    if (i < 768 * 1024) {
        int n = i >> 10, k = i & 1023;
        const float* src = (n < 256) ? (Wi + (size_t)n * 1024 + k)
                         : (n < 512) ? (Wf + (size_t)(n - 256) * 1280 + k)
                                     : (Wu + (size_t)(n - 512) * 1280 + k);
        W3b[i] = f2bf(*src);
    } else {
        int j = i - 768 * 1024;   // 0 .. 1024*1280-1
        Wob[j] = f2bf(Wo[j]);
    }
}

// ---------------------------------------------------------------------------
// Tiled bf16 MFMA GEMM: C[gr][gc] = sum_k A[gr][k]*B[gc][k]
// 128x128 tile, BK=32, 256 threads (4 waves, 2x2), global_load_lds staging.
// EPI=1: bias + silu(first 256 cols), bf16 out to xmfu[gr][gc] ([b*2048+t][768])
// EPI=2: + bo[gc] + x[gr][gc] residual, fp32 out to d_out
// ---------------------------------------------------------------------------
template <int EPI>
__global__ __launch_bounds__(256) void gemm_bt(const short* __restrict__ A,
                                               const short* __restrict__ Bmat,
                                               const int K, const int lda,
                                               const float* __restrict__ bias1,
                                               const float* __restrict__ bias2,
                                               const float* __restrict__ bias3,
                                               const float* __restrict__ xres,
                                               float* __restrict__ outf,
                                               short* __restrict__ outb) {
    __shared__ __align__(16) short As[4096];
    __shared__ __align__(16) short Bs[4096];

    const int tid = threadIdx.x;
    const int lane = tid & 63;
    const int wv = tid >> 6;
    const int wm = wv >> 1, wn = wv & 1;
    const int row15 = lane & 15;
    const int q = lane >> 4;
    const int tileM = blockIdx.x * 128;
    const int tileN = blockIdx.y * 128;

    float4v acc[4][4];
#pragma unroll
    for (int i = 0; i < 4; ++i)
#pragma unroll
        for (int j = 0; j < 4; ++j) acc[i][j] = {0.f, 0.f, 0.f, 0.f};

    const short* aG = A + (size_t)(tileM + (tid >> 2)) * lda + (tid & 3) * 8;
    const short* bG = Bmat + (size_t)(tileN + (tid >> 2)) * K + (tid & 3) * 8;
    const size_t aStep = (size_t)64 * lda;
    const size_t bStep = (size_t)64 * K;

    lds_u32* AsL = (lds_u32*)As;
    lds_u32* BsL = (lds_u32*)Bs;
    const int base1 = wv * 256;
    const int base2 = 1024 + wv * 256;

    for (int kt = 0; kt < K; kt += 32) {
        __builtin_amdgcn_global_load_lds((gl_u32*)aG,           AsL + base1, 16, 0, 0);
        __builtin_amdgcn_global_load_lds((gl_u32*)(aG + aStep), AsL + base2, 16, 0, 0);
        __builtin_amdgcn_global_load_lds((gl_u32*)bG,           BsL + base1, 16, 0, 0);
        __builtin_amdgcn_global_load_lds((gl_u32*)(bG + bStep), BsL + base2, 16, 0, 0);
        aG += 32; bG += 32;
        __syncthreads();

        short8 af[4], bf8[4];
#pragma unroll
        for (int mt = 0; mt < 4; ++mt)
            af[mt] = *(const short8*)(As + (wm * 64 + mt * 16 + row15) * 32 + q * 8);
#pragma unroll
        for (int nt = 0; nt < 4; ++nt)
            bf8[nt] = *(const short8*)(Bs + (wn * 64 + nt * 16 + row15) * 32 + q * 8);
#pragma unroll
        for (int mt = 0; mt < 4; ++mt)
#pragma unroll
            for (int nt = 0; nt < 4; ++nt)
                acc[mt][nt] = __builtin_amdgcn_mfma_f32_16x16x32_bf16(af[mt], bf8[nt], acc[mt][nt], 0, 0, 0);
        __syncthreads();
    }

#pragma unroll
    for (int mt = 0; mt < 4; ++mt) {
#pragma unroll
        for (int nt = 0; nt < 4; ++nt) {
#pragma unroll
            for (int r = 0; r < 4; ++r) {
                const int gr = tileM + wm * 64 + mt * 16 + q * 4 + r;
                const int gc = tileN + wn * 64 + nt * 16 + row15;
                float v = acc[mt][nt][r];
                if (EPI == 1) {
                    float bias = (gc < 256) ? bias1[gc] : (gc < 512) ? bias2[gc - 256] : bias3[gc - 512];
                    float z = v + bias;
                    if (gc < 256) z = z * sigmoidf_(z);   // silu for xm
                    outb[(size_t)gr * 768 + gc] = f2bf(z);
                } else {
                    const size_t idx = (size_t)gr * 1024 + gc;
                    outf[idx] = v + bias1[gc] + xres[idx];
                }
            }
        }
    }
}

// ---------------------------------------------------------------------------
// Sequential scan, ONE WORKGROUP PER BATCH (grid=16, 512 threads = 8 waves).
// R4: latency-lean step loop.
//  - A-operand reads are UNCONDITIONAL BROADCAST ds_read_b128 (all 64 lanes
//    load the same h slice; A = 16 identical rows of h, row 0 exact). No
//    exec-mask churn -> all 8 reads issue back-to-back, ONE LDS latency/step.
//  - No sched_barrier(0) in the loop: normal SSA loads order the MFMAs; the
//    only fences are {lgkmcnt(0); s_barrier; ""} with memory clobbers.
//  - acc zero-init folded into ks=0/1 MFMAs via a shared zero-C vector.
//  - waves 0-3 stage xmfu blocks via global_load_lds (vmcnt(0) once per 8
//    steps, queue contains only 7-step-aged loads); waves 4-7 copy finished
//    h blocks (hist ring) to Xcat as coalesced short8 stores.
// ---------------------------------------------------------------------------
__global__ __launch_bounds__(512, 2) void scan_kernel(const float* __restrict__ Wfp,
                                                      const float* __restrict__ Wup,
                                                      const short* __restrict__ xmfu,
                                                      short* __restrict__ Xcat,
                                                      float* __restrict__ hfinal) {
    __shared__ __align__(16) short hist[2][8][256];   // 8 KB: h bf16 history ring
    __shared__ __align__(16) short xstage[2][6144];   // 24 KB: 8 steps x [xm|xf|xu]

    const int tid = threadIdx.x;
    const int lane = tid & 63;
    const int w = tid >> 6;          // 0..7
    const int n0 = w * 32;           // this wave's 32 output columns
    const int row15 = lane & 15;
    const int q = lane >> 4;
    const int b = blockIdx.x;

    const short* xm_b = xmfu + (size_t)b * 1572864;   // [b][2048][768]
    short* XoutBase = Xcat + (size_t)b * 2048 * 1280 + 1024;

    for (int i = tid; i < 4096; i += 512) ((short*)hist)[i] = 0;

    // B-fragments for BOTH gates: B[k][n] = WH[n][1024+k]; lane holds
    // n = n0 + nt*16 + row15, k = ks*32 + q*8 + j.  32 short8 = 128 VGPRs.
    short8 bfrag[8][2][2];           // [ks][sel:f,u][nt]
#pragma unroll
    for (int ks = 0; ks < 8; ++ks)
#pragma unroll
        for (int sel = 0; sel < 2; ++sel)
#pragma unroll
            for (int nt = 0; nt < 2; ++nt) {
                const float* WH = sel ? Wup : Wfp;
                const float* src = WH + (size_t)(n0 + nt * 16 + row15) * 1280 + 1024 + ks * 32 + q * 8;
                float4v v0 = *(const float4v*)(src);
                float4v v1 = *(const float4v*)(src + 4);
                short8 v;
#pragma unroll
                for (int j = 0; j < 4; ++j) { v[j] = f2bf(v0[j]); v[j + 4] = f2bf(v1[j]); }
                bfrag[ks][sel][nt] = v;
            }

    lds_u32* xl = (lds_u32*)(&xstage[0][0]);
    const bool isLoader = (w < 4);   // waves 0-3 stage xmfu blocks
    const bool isCopier = (w >= 4);  // waves 4-7 copy hist -> Xcat

    if (isLoader) {
#pragma unroll
        for (int i = 0; i < 3; ++i)
            __builtin_amdgcn_global_load_lds((gl_u32*)(xm_b + i * 2048 + w * 512 + lane * 8),
                                             xl + (i * 1024 + w * 256), 16, 0, 0);
        asm volatile("s_waitcnt vmcnt(0)" ::: "memory");
    }
    asm volatile("s_waitcnt lgkmcnt(0)" ::: "memory");
    __builtin_amdgcn_s_barrier();
    asm volatile("" ::: "memory");

    // in-register recurrence state: lane l (<16) of wave w owns
    // h[m1 = n0 + l] and h[m2 = n0 + 16 + l]
    float h1 = 0.f, h2 = 0.f;
    const int m1 = n0 + row15;

    // copier geometry: this lane copies hist row s0r (2 rows per wave)
    const int s0r = 2 * (w - 4) + (lane >> 5);
    const int cOff = (lane & 31) * 8;

#pragma unroll 1
    for (int j = 0; j < 256; ++j) {
        const int jb = j & 1;
        if (isLoader && (j + 1 < 256)) {
            const short* src = xm_b + (size_t)(j + 1) * 6144;
#pragma unroll
            for (int i = 0; i < 3; ++i)
                __builtin_amdgcn_global_load_lds((gl_u32*)(src + i * 2048 + w * 512 + lane * 8),
                                                 xl + ((jb ^ 1) * 3072 + i * 1024 + w * 256), 16, 0, 0);
        }
        if (isCopier && j >= 1) {
            // previous block's h (parity jb^1) -> Xcat, coalesced 512B rows
            short8 hv = *(const short8*)(&hist[jb ^ 1][s0r][cOff]);
            *(short8*)(XoutBase + (size_t)(8 * (j - 1) + s0r) * 1280 + cOff) = hv;
        }
        const short* xs = &xstage[jb][0];
#pragma unroll
        for (int s = 0; s < 8; ++s) {
            // h_{t-1} source: previous step's row (block-parity ring)
            const short* hprev = (s == 0) ? &hist[jb ^ 1][7][0] : &hist[jb][s - 1][0];

            // broadcast A-frag reads: ALL lanes load the same h slice
            // (A = 16 identical rows; output row 0 exact). 4 distinct 16B
            // addrs/wave per ks -> disjoint banks, conflict-free.
            short8 hk[8];
#pragma unroll
            for (int ks = 0; ks < 8; ++ks)
                hk[ks] = *(const short8*)(hprev + ks * 32 + q * 8);

            // xm / logit-bias loads (all lanes; >=16 read duplicates)
            const float xmv1 = bf2f(xs[s * 768 + m1]);
            const float zf1  = bf2f(xs[s * 768 + 256 + m1]);
            const float zu1  = bf2f(xs[s * 768 + 512 + m1]);
            const float xmv2 = bf2f(xs[s * 768 + 16 + m1]);
            const float zf2  = bf2f(xs[s * 768 + 272 + m1]);
            const float zu2  = bf2f(xs[s * 768 + 528 + m1]);

            // logits, both gates; even/odd-ks chain split (8 chains, depth 4).
            // ks=0/1 initialize accs via zero-C MFMA (no per-step acc zeroing).
            const float4v z4 = {0.f, 0.f, 0.f, 0.f};
            float4v acc[2][2][2];   // [sel][nt][half]
#pragma unroll
            for (int ks = 0; ks < 8; ++ks) {
                const int hf = ks & 1;
#pragma unroll
                for (int sel = 0; sel < 2; ++sel)
#pragma unroll
                    for (int nt = 0; nt < 2; ++nt)
                        acc[sel][nt][hf] = __builtin_amdgcn_mfma_f32_16x16x32_bf16(
                            hk[ks], bfrag[ks][sel][nt],
                            (ks < 2) ? z4 : acc[sel][nt][hf], 0, 0, 0);
            }

            // row 0 (the real batch row) = lanes 0..15, reg 0
            if (lane < 16) {
                const float f1 = sigmoidf_(acc[0][0][0][0] + acc[0][0][1][0] + zf1);
                const float u1 = sigmoidf_(acc[1][0][0][0] + acc[1][0][1][0] + zu1);
                const float f2 = sigmoidf_(acc[0][1][0][0] + acc[0][1][1][0] + zf2);
                const float u2 = sigmoidf_(acc[1][1][0][0] + acc[1][1][1][0] + zu2);
                h1 = f1 * h1 + u1 * xmv1;
                h2 = f2 * h2 + u2 * xmv2;
                hist[jb][s][m1] = f2bf(h1);
                hist[jb][s][m1 + 16] = f2bf(h2);
            }
            if (s == 7 && isLoader)   // next block's loads must be in LDS
                asm volatile("s_waitcnt vmcnt(0)" ::: "memory");
            asm volatile("s_waitcnt lgkmcnt(0)" ::: "memory");
            __builtin_amdgcn_s_barrier();
            asm volatile("" ::: "memory");
        }
    }
    // tail: copy the final block's h (parity 1, t = 2040..2047)
    if (isCopier) {
        short8 hv = *(const short8*)(&hist[1][s0r][cOff]);
        *(short8*)(XoutBase + (size_t)(2040 + s0r) * 1280 + cOff) = hv;
    }
    if (lane < 16) {
        hfinal[b * 256 + m1] = h1;
        hfinal[b * 256 + m1 + 16] = h2;
    }
}

// ---------------------------------------------------------------------------
extern "C" void kernel_launch(void* const* d_in, const int* in_sizes, int n_in,
                              void* d_out, int out_size, void* d_ws, size_t ws_size,
                              hipStream_t stream) {
    const float* x  = (const float*)d_in[0];
    const float* Wi = (const float*)d_in[1];
    const float* bi = (const float*)d_in[2];
    const float* Wf = (const float*)d_in[3];
    const float* bf = (const float*)d_in[4];
    const float* Wu = (const float*)d_in[5];
    const float* bu = (const float*)d_in[6];
    const float* Wo = (const float*)d_in[7];
    const float* bo = (const float*)d_in[8];
    float* out = (float*)d_out;   // 33554432 outs + 4096 h_final

    char* ws = (char*)d_ws;
    short* Xcat = (short*)ws;                                  // 32768*1280*2 = 83,886,080 B
    short* xmfu = (short*)(ws + 83886080ULL);                  // [b][t][768]: 50,331,648 B
    short* W3b  = (short*)(ws + 83886080ULL + 50331648ULL);    // 768*1024*2
    short* Wob  = (short*)(ws + 83886080ULL + 50331648ULL + 1572864ULL); // 1024*1280*2

    xconvert_kernel<<<dim3(32768), dim3(256), 0, stream>>>(x, Xcat);
    wconvert_kernel<<<dim3(8192), dim3(256), 0, stream>>>(Wi, Wf, Wu, Wo, W3b, Wob);
    // xm/xf/xu: (32768 x 768) = Xcat[:, :1024] @ W3b^T (+bias, silu on xm)
    gemm_bt<1><<<dim3(256, 6), dim3(256), 0, stream>>>(Xcat, W3b, 1024, 1280,
                                                       bi, bf, bu, nullptr, nullptr, xmfu);
    // sequential recurrence: 16 independent batch workgroups
    scan_kernel<<<dim3(16), dim3(512), 0, stream>>>(Wf, Wu, xmfu, Xcat, out + 33554432);
    // out = x + Xcat @ Wo^T + bo   (covers x@Wo[:,:d]^T + H@WoH^T)
    gemm_bt<2><<<dim3(256, 8), dim3(256), 0, stream>>>(Xcat, Wob, 1280, 1280,
                                                       bo, nullptr, nullptr, x, out, nullptr);
}